// Round 17
// baseline (348.003 us; speedup 1.0000x reference)
//
#include <hip/hip_runtime.h>

#define DD 128

typedef short s16x8 __attribute__((ext_vector_type(8)));
typedef float f32x4 __attribute__((ext_vector_type(4)));

// tanh via hardware rcp: 1 - 2/(e^{2x}+1). v_rcp_f32 is ~1 ulp.
__device__ __forceinline__ float tanh_fast(float x) {
  float e = __expf(2.0f * x);
  float r = __builtin_amdgcn_rcpf(e + 1.0f);
  return fmaf(-2.0f, r, 1.0f);
}

// f32 -> bf16 round-to-nearest-even
__device__ __forceinline__ unsigned short f2bf(float f) {
  unsigned u = __float_as_uint(f);
  u += 0x7FFFu + ((u >> 16) & 1u);
  return (unsigned short)(u >> 16);
}

__device__ __forceinline__ float bf2f(unsigned short u) {
  return __uint_as_float(((unsigned)u) << 16);
}

// unpack bf16 pair word: odd ? hi : lo  (1 VALU op each)
__device__ __forceinline__ float bfu(unsigned w, int odd) {
  return __uint_as_float(odd ? (w & 0xFFFF0000u) : (w << 16));
}

// 16-lane butterfly sum via update_dpp (compiler inserts the GFX9 DPP
// wait-states; raw inline-asm v_add_f32_dpp reads stale VGPRs -- round-15 bug).
// dpp_ctrl must be an integer-constant expression -> template parameter.
// ctrl: quad_perm[1,0,3,2]=0xB1, quad_perm[2,3,0,1]=0x4E,
//       row_ror:4=0x124, row_ror:8=0x128. DPP row = 16 lanes.
template <int CTRL>
__device__ __forceinline__ float dpp_add(float x) {
  float t = __uint_as_float(
      __builtin_amdgcn_update_dpp(0, __float_as_uint(x), CTRL, 0xF, 0xF, false));
  return x + t;
}
__device__ __forceinline__ float red16_dpp(float x) {
  x = dpp_add<0xB1>(x);
  x = dpp_add<0x4E>(x);
  x = dpp_add<0x124>(x);
  x = dpp_add<0x128>(x);
  return x;
}

// ---- misc pass: [0,16) packw1 | [16,32) packw2 | [32,32+hb) ER hist |
//      [32+hb, 32+hb+db) EE weighted degree ----
extern "C" __global__ __launch_bounds__(256) void k_misc(
    const float* __restrict__ Wattn, unsigned short* __restrict__ WB,
    const float* __restrict__ Wself, const float* __restrict__ Wneigh,
    unsigned short* __restrict__ WBh, unsigned short* __restrict__ WBl,
    const int* __restrict__ er_src, int* __restrict__ count, int nER, int hb,
    const int* __restrict__ ee_src, const float* __restrict__ ee_w,
    float* __restrict__ g, int nEE) {
  const int b = blockIdx.x;
  const int tid = threadIdx.x;
  if (b < 16) {
    int t = b * 256 + tid;      // 0..4095
    int lane = t & 63;
    int cks = t >> 6;           // ct*4+ks
    int ks = cks & 3, ct = cks >> 2;
    int c = ct * 16 + (lane & 15);
    int kb = ks * 32 + ((lane >> 4) << 3);
    const float* srcp = (c < DD) ? (Wattn + (size_t)kb * DD + c)
                                 : (Wattn + (size_t)(DD + kb) * DD + (c - DD));
    unsigned short* dst = WB + (size_t)t * 8;
#pragma unroll
    for (int j = 0; j < 8; ++j) dst[j] = f2bf(srcp[(size_t)j * DD]);
  } else if (b < 32) {
    int t = (b - 16) * 256 + tid;  // 0..4095
    int lane = t & 63;
    int cks = t >> 6;           // ct*8+ks
    int ks = cks & 7, ct = cks >> 3;
    int c = ct * 16 + (lane & 15);
    int k0 = ks * 32 + ((lane >> 4) << 3);
#pragma unroll
    for (int j = 0; j < 8; ++j) {
      int k = k0 + j;
      float v = (k < DD) ? Wself[(size_t)k * DD + c]
                         : Wneigh[(size_t)(k - DD) * DD + c];
      unsigned short h = f2bf(v);
      float r = v - bf2f(h);
      WBh[(size_t)t * 8 + j] = h;
      WBl[(size_t)t * 8 + j] = f2bf(r);
    }
  } else if (b < 32 + hb) {
    int e = (b - 32) * 256 + tid;
    if (e < nER) atomicAdd(&count[er_src[e]], 1);
  } else {
    int e = (b - 32 - hb) * 256 + tid;
    if (e < nEE) unsafeAtomicAdd(&g[ee_src[e]], ee_w[e]);
  }
}

// PQE[v] (stride 384 shorts): [0:128)=P, [128:256)=E, [256:384)=Q, bf16.
// Staged in LDS, then one contiguous coalesced write.
extern "C" __global__ __launch_bounds__(256) void k_pq_mfma(
    const float* __restrict__ emb, const unsigned short* __restrict__ WB,
    const float* __restrict__ battn, unsigned short* __restrict__ PQE, int n) {
  __shared__ unsigned short S[64][388];
  const int wave = threadIdx.x >> 6, lane = threadIdx.x & 63;
  const int v0b = blockIdx.x * 64;
  const int v0 = v0b + wave * 16;
  const int row = v0 + (lane & 15);
  const int lr = wave * 16 + (lane & 15);
  const int kb = (lane >> 4) << 3;
  const bool rok = row < n;
  s16x8 a[4];
#pragma unroll
  for (int ks = 0; ks < 4; ++ks) {
    unsigned short tmp[8] = {0, 0, 0, 0, 0, 0, 0, 0};
    if (rok) {
      float4 xa = *(const float4*)(emb + (size_t)row * DD + ks * 32 + kb);
      float4 xb = *(const float4*)(emb + (size_t)row * DD + ks * 32 + kb + 4);
      tmp[0] = f2bf(xa.x); tmp[1] = f2bf(xa.y);
      tmp[2] = f2bf(xa.z); tmp[3] = f2bf(xa.w);
      tmp[4] = f2bf(xb.x); tmp[5] = f2bf(xb.y);
      tmp[6] = f2bf(xb.z); tmp[7] = f2bf(xb.w);
    }
    a[ks] = *(const s16x8*)tmp;
    *(s16x8*)&S[lr][128 + ks * 32 + kb] = a[ks];   // E copy
  }
  f32x4 acc[16];
#pragma unroll
  for (int ct = 0; ct < 16; ++ct) acc[ct] = (f32x4)(0.f);
  const s16x8* wb = (const s16x8*)WB;
#pragma unroll
  for (int ct = 0; ct < 16; ++ct) {
#pragma unroll
    for (int ks = 0; ks < 4; ++ks) {
      s16x8 b = wb[(ct * 4 + ks) * 64 + lane];
      acc[ct] = __builtin_amdgcn_mfma_f32_16x16x32_bf16(a[ks], b, acc[ct], 0, 0, 0);
    }
  }
  const int r0 = (lane >> 4) << 2;
  const int col0 = lane & 15;
#pragma unroll
  for (int ct = 0; ct < 16; ++ct) {
    int c = ct * 16 + col0;
    float bias = (c < DD) ? battn[c] : 0.f;
    int dsto = (c < DD) ? c : (c + DD);   // P at [0,128), Q at [256,384)
#pragma unroll
    for (int r = 0; r < 4; ++r)
      S[wave * 16 + r0 + r][dsto] = f2bf(acc[ct][r] + bias);
  }
  __syncthreads();
  const int tid = threadIdx.x;
#pragma unroll
  for (int i = 0; i < 12; ++i) {
    int idx = tid + i * 256;          // 0..3071
    int rr = idx / 48, k8 = idx - rr * 48;
    if (v0b + rr < n) {
      uint4 val = *(const uint4*)&S[rr][k8 * 8];
      *(uint4*)(PQE + (size_t)(v0b + rr) * 384 + k8 * 8) = val;
    }
  }
}

// Blelloch exclusive scan, 512 elems/block; bsum[b] = chunk total
extern "C" __global__ __launch_bounds__(256) void k_scan(
    const int* __restrict__ in, int* __restrict__ outp,
    int* __restrict__ bsum, int n) {
  __shared__ int s[512];
  __shared__ int total;
  const int t = threadIdx.x;
  const int base = blockIdx.x * 512;
  for (int i = t; i < 512; i += 256) s[i] = (base + i < n) ? in[base + i] : 0;
  __syncthreads();
  for (int d = 1; d < 512; d <<= 1) {
    int stride = d * 2;
    int nidx = 512 / stride;
    if (t < nidx) {
      int idx = (t + 1) * stride - 1;
      s[idx] += s[idx - d];
    }
    __syncthreads();
  }
  if (t == 0) { total = s[511]; s[511] = 0; }
  __syncthreads();
  for (int d = 256; d >= 1; d >>= 1) {
    int stride = d * 2;
    int nidx = 512 / stride;
    if (t < nidx) {
      int idx = (t + 1) * stride - 1;
      int tmp = s[idx - d];
      s[idx - d] = s[idx];
      s[idx] += tmp;
    }
    __syncthreads();
  }
  for (int i = t; i < 512; i += 256)
    if (base + i < n) outp[base + i] = s[i];
  if (t == 0) bsum[blockIdx.x] = total;
}

// adds chunk offsets; writes BOTH off and off_mut
extern "C" __global__ __launch_bounds__(256) void k_scan_add(
    int* __restrict__ off, int* __restrict__ off_mut,
    const int* __restrict__ bofs, int n, int total) {
  int base = blockIdx.x * 512;
  int add = bofs[blockIdx.x];
  for (int i = threadIdx.x; i < 512; i += 256) {
    int idx = base + i;
    if (idx < n) {
      int val = off[idx] + add;
      off[idx] = val;
      off_mut[idx] = val;
    }
  }
  if (blockIdx.x == 0 && threadIdx.x == 0) off[n] = total;
}

// counting-sort the dst indices by src: dst_s[off[src]++] = dst
extern "C" __global__ __launch_bounds__(256) void k_scatter_dst(
    const int* __restrict__ src, const int* __restrict__ dstp,
    int* __restrict__ off_mut, int* __restrict__ dst_s, int nE) {
  int e = blockIdx.x * 256 + threadIdx.x;
  if (e >= nE) return;
  int pos = atomicAdd(&off_mut[src[e]], 1);
  dst_s[pos] = dstp[e];
}

// Fused edge phase. One wave per node, 4 groups x 16 lanes, one edge per
// group-iter, prefetch-1 pipeline. No max subtraction (|s| bounded; ratio
// algebraically identical).
// Folded algebra: sum_j tanh(P_j+Q_j) w_j = Wl - sum_j 2 w_j r_j,
//   r_j = 1/(exp2(K(P_j+Q_j)) + 1), K = 2 log2(e), Wl = sum_j w_j.
// p = exp(s+wb) = exp2(fma(nps, -log2e, C2)), C2 = log2e*(Wl+wb).
// In-loop 16-lane reduce via update_dpp butterfly (VALU pipe, no LDS ops).
extern "C" __global__ __launch_bounds__(256) void k_fused(
    const unsigned short* __restrict__ PQE, const int* __restrict__ off,
    const int* __restrict__ dst_s, const float* __restrict__ w0w,
    const float* __restrict__ w0b, float* __restrict__ U,
    float* __restrict__ ssum, int n) {
  int v = (blockIdx.x * 256 + threadIdx.x) >> 6;
  int lane = threadIdx.x & 63;
  if (v >= n) return;
  const int l16 = lane & 15;
  const int grp = lane >> 4;
  const int start = off[v], end = off[v + 1];
  const float K = 2.8853900817779268f;   // 2*log2(e)
  const float L2E = 1.4426950408889634f;
  float q2[8], w2[8];
  float Wl = 0.f;
  {
    uint4 qv = *(const uint4*)(PQE + (size_t)v * 384 + 256 + l16 * 8);
    unsigned qq[4] = {qv.x, qv.y, qv.z, qv.w};
    float4 wa = *(const float4*)&w0w[l16 * 8];
    float4 wc = *(const float4*)&w0w[l16 * 8 + 4];
    float wv[8] = {wa.x, wa.y, wa.z, wa.w, wc.x, wc.y, wc.z, wc.w};
#pragma unroll
    for (int j = 0; j < 8; ++j) {
      q2[j] = K * bfu(qq[j >> 1], j & 1);
      w2[j] = 2.0f * wv[j];
      Wl += wv[j];
    }
  }
  Wl = red16_dpp(Wl);
  const float C2 = (Wl + w0b[0]) * L2E;
  float a[8] = {0.f, 0.f, 0.f, 0.f, 0.f, 0.f, 0.f, 0.f};
  float ssv = 0.f;
  int i = start + grp;
  uint4 pv, ev;
  if (i < end) {
    const unsigned short* pe = PQE + (size_t)dst_s[i] * 384 + l16 * 8;
    pv = *(const uint4*)pe;
    ev = *(const uint4*)(pe + 128);
  }
  while (i < end) {
    int inx = i + 4;
    uint4 pvn, evn;
    if (inx < end) {
      const unsigned short* pen = PQE + (size_t)dst_s[inx] * 384 + l16 * 8;
      pvn = *(const uint4*)pen;
      evn = *(const uint4*)(pen + 128);
    }
    unsigned pw[4] = {pv.x, pv.y, pv.z, pv.w};
    unsigned ew[4] = {ev.x, ev.y, ev.z, ev.w};
    float np = 0.f;
#pragma unroll
    for (int j = 0; j < 8; ++j) {
      float x = bfu(pw[j >> 1], j & 1);
      float e = exp2f(fmaf(x, K, q2[j]));
      float r = __builtin_amdgcn_rcpf(e + 1.0f);
      np = fmaf(w2[j], r, np);
    }
    np = red16_dpp(np);
    float p = exp2f(fmaf(np, -L2E, C2));
    ssv += p;
#pragma unroll
    for (int j = 0; j < 8; ++j)
      a[j] = fmaf(p, bfu(ew[j >> 1], j & 1), a[j]);
    i = inx;
    pv = pvn;
    ev = evn;
  }
  // merge the 4 groups (disjoint edge subsets, same dim ownership)
#pragma unroll
  for (int j = 0; j < 8; ++j) {
    a[j] += __shfl_xor(a[j], 16);
    a[j] += __shfl_xor(a[j], 32);
  }
  ssv += __shfl_xor(ssv, 16);
  ssv += __shfl_xor(ssv, 32);
  if (grp == 0) {
    float4 o0 = make_float4(a[0], a[1], a[2], a[3]);
    float4 o1 = make_float4(a[4], a[5], a[6], a[7]);
    *(float4*)(U + (size_t)v * DD + l16 * 8) = o0;
    *(float4*)(U + (size_t)v * DD + l16 * 8 + 4) = o1;
    if (l16 == 0) ssum[v] = ssv;
  }
}

// out = tanh([emb | M] @ [Wself;Wneigh] + bself + tg*bneigh), M = U*inv + g*emb.
// Split-precision bf16 hi/lo: acc = AhBh + AlBh + AhBl.
extern "C" __global__ __launch_bounds__(256) void k_out_mfma(
    const float* __restrict__ emb, const float* __restrict__ U,
    const float* __restrict__ ssum, const float* __restrict__ g,
    const unsigned short* __restrict__ WBh, const unsigned short* __restrict__ WBl,
    const float* __restrict__ bself, const float* __restrict__ bneigh,
    float* __restrict__ out, int n) {
  const int wave = threadIdx.x >> 6, lane = threadIdx.x & 63;
  const int v0 = blockIdx.x * 64 + wave * 16;
  const int row = v0 + (lane & 15);
  const int kb = (lane >> 4) << 3;
  const bool rok = row < n;
  float inv = 0.f, gv = 0.f;
  if (rok) {
    float sv = ssum[row];
    inv = 1.f / (sv + 1e-9f);
    gv = g[row];
  }
  s16x8 ah[8], al[8];
#pragma unroll
  for (int ks = 0; ks < 8; ++ks) {
    int k0 = (ks & 3) * 32 + kb;
    float x[8] = {0.f, 0.f, 0.f, 0.f, 0.f, 0.f, 0.f, 0.f};
    if (rok) {
      float4 ea = *(const float4*)(emb + (size_t)row * DD + k0);
      float4 eb = *(const float4*)(emb + (size_t)row * DD + k0 + 4);
      x[0] = ea.x; x[1] = ea.y; x[2] = ea.z; x[3] = ea.w;
      x[4] = eb.x; x[5] = eb.y; x[6] = eb.z; x[7] = eb.w;
      if (ks >= 4) {
        float4 ua = *(const float4*)(U + (size_t)row * DD + k0);
        float4 ub = *(const float4*)(U + (size_t)row * DD + k0 + 4);
        x[0] = fmaf(gv, x[0], ua.x * inv);
        x[1] = fmaf(gv, x[1], ua.y * inv);
        x[2] = fmaf(gv, x[2], ua.z * inv);
        x[3] = fmaf(gv, x[3], ua.w * inv);
        x[4] = fmaf(gv, x[4], ub.x * inv);
        x[5] = fmaf(gv, x[5], ub.y * inv);
        x[6] = fmaf(gv, x[6], ub.z * inv);
        x[7] = fmaf(gv, x[7], ub.w * inv);
      }
    }
    unsigned short hh[8], ll[8];
#pragma unroll
    for (int j = 0; j < 8; ++j) {
      unsigned short h = f2bf(x[j]);
      hh[j] = h;
      ll[j] = f2bf(x[j] - bf2f(h));
    }
    ah[ks] = *(const s16x8*)hh;
    al[ks] = *(const s16x8*)ll;
  }
  f32x4 acc[8];
#pragma unroll
  for (int ct = 0; ct < 8; ++ct) acc[ct] = (f32x4)(0.f);
  const s16x8* wbh = (const s16x8*)WBh;
  const s16x8* wbl = (const s16x8*)WBl;
#pragma unroll
  for (int ct = 0; ct < 8; ++ct) {
#pragma unroll
    for (int ks = 0; ks < 8; ++ks) {
      s16x8 bh = wbh[(ct * 8 + ks) * 64 + lane];
      s16x8 bl = wbl[(ct * 8 + ks) * 64 + lane];
      acc[ct] = __builtin_amdgcn_mfma_f32_16x16x32_bf16(ah[ks], bh, acc[ct], 0, 0, 0);
      acc[ct] = __builtin_amdgcn_mfma_f32_16x16x32_bf16(al[ks], bh, acc[ct], 0, 0, 0);
      acc[ct] = __builtin_amdgcn_mfma_f32_16x16x32_bf16(ah[ks], bl, acc[ct], 0, 0, 0);
    }
  }
  const int r0 = (lane >> 4) << 2;
  const int col0 = lane & 15;
  float tgr[4];
#pragma unroll
  for (int r = 0; r < 4; ++r) {
    int v = v0 + r0 + r;
    float tg = 0.f;
    if (v < n) {
      float sv = ssum[v];
      tg = sv / (sv + 1e-9f) + g[v];
    }
    tgr[r] = tg;
  }
#pragma unroll
  for (int ct = 0; ct < 8; ++ct) {
    int c = ct * 16 + col0;
    float bs = bself[c], bn = bneigh[c];
#pragma unroll
    for (int r = 0; r < 4; ++r) {
      int v = v0 + r0 + r;
      if (v < n) out[(size_t)v * DD + c] = tanh_fast(acc[ct][r] + bs + tgr[r] * bn);
    }
  }
}

static inline size_t al16(size_t x) { return (x + 15) & ~(size_t)15; }

extern "C" void kernel_launch(void* const* d_in, const int* in_sizes, int n_in,
                              void* d_out, int out_size, void* d_ws, size_t ws_size,
                              hipStream_t stream) {
  const float* emb = (const float*)d_in[0];
  const int* er_src = (const int*)d_in[1];
  const int* er_dst = (const int*)d_in[2];
  const int* ee_src = (const int*)d_in[3];
  const float* ee_w = (const float*)d_in[5];
  const float* Wattn = (const float*)d_in[6];
  const float* battn = (const float*)d_in[7];
  const float* w0w = (const float*)d_in[8];
  const float* w0b = (const float*)d_in[9];
  const float* Wself = (const float*)d_in[10];
  const float* bself = (const float*)d_in[11];
  const float* Wneigh = (const float*)d_in[12];
  const float* bneigh = (const float*)d_in[13];
  const int n = in_sizes[0] / DD;
  const int nER = in_sizes[1];
  const int nEE = in_sizes[3];

  // workspace layout (16B-aligned slices)
  char* w = (char*)d_ws;
  size_t o = 0;
  unsigned short* PQE = (unsigned short*)(w + o); o += al16((size_t)n * 384 * 2);
  float* U = (float*)(w + o);   o += al16((size_t)n * DD * 4);
  int* dst_s = (int*)(w + o);   o += al16((size_t)nER * 4);
  int* count = (int*)(w + o);   o += al16((size_t)n * 4);
  float* g = (float*)(w + o);   o += al16((size_t)n * 4);   // adjacent to count
  int* off = (int*)(w + o);     o += al16((size_t)(n + 4) * 4);
  int* off_mut = (int*)(w + o); o += al16((size_t)n * 4);
  float* ssum = (float*)(w + o); o += al16((size_t)n * 4);
  unsigned short* WB = (unsigned short*)(w + o);   o += 65536;
  unsigned short* WB2h = (unsigned short*)(w + o); o += 65536;
  unsigned short* WB2l = (unsigned short*)(w + o); o += 65536;
  int* bsum = (int*)(w + o);    o += 4096;
  int* dummy = (int*)(w + o);   o += 64;

  const int nb = (n + 511) / 512;
  const int hb = (nER + 255) / 256;
  const int db = (nEE + 255) / 256;

  hipMemsetAsync(count, 0, (size_t)n * 8, stream);  // count + g

  k_misc<<<32 + hb + db, 256, 0, stream>>>(Wattn, WB, Wself, Wneigh, WB2h, WB2l,
                                           er_src, count, nER, hb, ee_src, ee_w,
                                           g, nEE);
  k_pq_mfma<<<(n + 63) / 64, 256, 0, stream>>>(emb, WB, battn, PQE, n);
  k_scan<<<nb, 256, 0, stream>>>(count, off, bsum, n);
  k_scan<<<1, 256, 0, stream>>>(bsum, bsum, dummy, nb);
  k_scan_add<<<nb, 256, 0, stream>>>(off, off_mut, bsum, n, nER);
  k_scatter_dst<<<(nER + 255) / 256, 256, 0, stream>>>(er_src, er_dst, off_mut,
                                                       dst_s, nER);
  k_fused<<<(n + 3) / 4, 256, 0, stream>>>(PQE, off, dst_s, w0w, w0b,
                                           U, ssum, n);
  k_out_mfma<<<(n + 63) / 64, 256, 0, stream>>>(emb, U, ssum, g, WB2h, WB2l,
                                                bself, bneigh, (float*)d_out, n);
}

// Round 18
// 339.120 us; speedup vs baseline: 1.0262x; 1.0262x over previous
//
#include <hip/hip_runtime.h>

#define DD 128

typedef short s16x8 __attribute__((ext_vector_type(8)));
typedef float f32x4 __attribute__((ext_vector_type(4)));

// tanh via hardware rcp: 1 - 2/(e^{2x}+1). v_rcp_f32 is ~1 ulp.
__device__ __forceinline__ float tanh_fast(float x) {
  float e = __expf(2.0f * x);
  float r = __builtin_amdgcn_rcpf(e + 1.0f);
  return fmaf(-2.0f, r, 1.0f);
}

// f32 -> bf16 round-to-nearest-even
__device__ __forceinline__ unsigned short f2bf(float f) {
  unsigned u = __float_as_uint(f);
  u += 0x7FFFu + ((u >> 16) & 1u);
  return (unsigned short)(u >> 16);
}

__device__ __forceinline__ float bf2f(unsigned short u) {
  return __uint_as_float(((unsigned)u) << 16);
}

// unpack bf16 pair word: odd ? hi : lo  (1 VALU op each)
__device__ __forceinline__ float bfu(unsigned w, int odd) {
  return __uint_as_float(odd ? (w & 0xFFFF0000u) : (w << 16));
}

// ---- misc pass: [0,16) packw1 | [16,32) packw2 | [32,32+hb) ER hist |
//      [32+hb, 32+hb+db) EE weighted degree ----
extern "C" __global__ __launch_bounds__(256) void k_misc(
    const float* __restrict__ Wattn, unsigned short* __restrict__ WB,
    const float* __restrict__ Wself, const float* __restrict__ Wneigh,
    unsigned short* __restrict__ WBh, unsigned short* __restrict__ WBl,
    const int* __restrict__ er_src, int* __restrict__ count, int nER, int hb,
    const int* __restrict__ ee_src, const float* __restrict__ ee_w,
    float* __restrict__ g, int nEE) {
  const int b = blockIdx.x;
  const int tid = threadIdx.x;
  if (b < 16) {
    int t = b * 256 + tid;      // 0..4095
    int lane = t & 63;
    int cks = t >> 6;           // ct*4+ks
    int ks = cks & 3, ct = cks >> 2;
    int c = ct * 16 + (lane & 15);
    int kb = ks * 32 + ((lane >> 4) << 3);
    const float* srcp = (c < DD) ? (Wattn + (size_t)kb * DD + c)
                                 : (Wattn + (size_t)(DD + kb) * DD + (c - DD));
    unsigned short* dst = WB + (size_t)t * 8;
#pragma unroll
    for (int j = 0; j < 8; ++j) dst[j] = f2bf(srcp[(size_t)j * DD]);
  } else if (b < 32) {
    int t = (b - 16) * 256 + tid;  // 0..4095
    int lane = t & 63;
    int cks = t >> 6;           // ct*8+ks
    int ks = cks & 7, ct = cks >> 3;
    int c = ct * 16 + (lane & 15);
    int k0 = ks * 32 + ((lane >> 4) << 3);
#pragma unroll
    for (int j = 0; j < 8; ++j) {
      int k = k0 + j;
      float v = (k < DD) ? Wself[(size_t)k * DD + c]
                         : Wneigh[(size_t)(k - DD) * DD + c];
      unsigned short h = f2bf(v);
      float r = v - bf2f(h);
      WBh[(size_t)t * 8 + j] = h;
      WBl[(size_t)t * 8 + j] = f2bf(r);
    }
  } else if (b < 32 + hb) {
    int e = (b - 32) * 256 + tid;
    if (e < nER) atomicAdd(&count[er_src[e]], 1);
  } else {
    int e = (b - 32 - hb) * 256 + tid;
    if (e < nEE) unsafeAtomicAdd(&g[ee_src[e]], ee_w[e]);
  }
}

// PQE[v] (stride 384 shorts): [0:128)=P, [128:256)=E, [256:384)=Q, bf16.
// Staged in LDS, then one contiguous coalesced write.
extern "C" __global__ __launch_bounds__(256) void k_pq_mfma(
    const float* __restrict__ emb, const unsigned short* __restrict__ WB,
    const float* __restrict__ battn, unsigned short* __restrict__ PQE, int n) {
  __shared__ unsigned short S[64][388];
  const int wave = threadIdx.x >> 6, lane = threadIdx.x & 63;
  const int v0b = blockIdx.x * 64;
  const int v0 = v0b + wave * 16;
  const int row = v0 + (lane & 15);
  const int lr = wave * 16 + (lane & 15);
  const int kb = (lane >> 4) << 3;
  const bool rok = row < n;
  s16x8 a[4];
#pragma unroll
  for (int ks = 0; ks < 4; ++ks) {
    unsigned short tmp[8] = {0, 0, 0, 0, 0, 0, 0, 0};
    if (rok) {
      float4 xa = *(const float4*)(emb + (size_t)row * DD + ks * 32 + kb);
      float4 xb = *(const float4*)(emb + (size_t)row * DD + ks * 32 + kb + 4);
      tmp[0] = f2bf(xa.x); tmp[1] = f2bf(xa.y);
      tmp[2] = f2bf(xa.z); tmp[3] = f2bf(xa.w);
      tmp[4] = f2bf(xb.x); tmp[5] = f2bf(xb.y);
      tmp[6] = f2bf(xb.z); tmp[7] = f2bf(xb.w);
    }
    a[ks] = *(const s16x8*)tmp;
    *(s16x8*)&S[lr][128 + ks * 32 + kb] = a[ks];   // E copy
  }
  f32x4 acc[16];
#pragma unroll
  for (int ct = 0; ct < 16; ++ct) acc[ct] = (f32x4)(0.f);
  const s16x8* wb = (const s16x8*)WB;
#pragma unroll
  for (int ct = 0; ct < 16; ++ct) {
#pragma unroll
    for (int ks = 0; ks < 4; ++ks) {
      s16x8 b = wb[(ct * 4 + ks) * 64 + lane];
      acc[ct] = __builtin_amdgcn_mfma_f32_16x16x32_bf16(a[ks], b, acc[ct], 0, 0, 0);
    }
  }
  const int r0 = (lane >> 4) << 2;
  const int col0 = lane & 15;
#pragma unroll
  for (int ct = 0; ct < 16; ++ct) {
    int c = ct * 16 + col0;
    float bias = (c < DD) ? battn[c] : 0.f;
    int dsto = (c < DD) ? c : (c + DD);   // P at [0,128), Q at [256,384)
#pragma unroll
    for (int r = 0; r < 4; ++r)
      S[wave * 16 + r0 + r][dsto] = f2bf(acc[ct][r] + bias);
  }
  __syncthreads();
  const int tid = threadIdx.x;
#pragma unroll
  for (int i = 0; i < 12; ++i) {
    int idx = tid + i * 256;          // 0..3071
    int rr = idx / 48, k8 = idx - rr * 48;
    if (v0b + rr < n) {
      uint4 val = *(const uint4*)&S[rr][k8 * 8];
      *(uint4*)(PQE + (size_t)(v0b + rr) * 384 + k8 * 8) = val;
    }
  }
}

// Blelloch exclusive scan, 512 elems/block; bsum[b] = chunk total
extern "C" __global__ __launch_bounds__(256) void k_scan(
    const int* __restrict__ in, int* __restrict__ outp,
    int* __restrict__ bsum, int n) {
  __shared__ int s[512];
  __shared__ int total;
  const int t = threadIdx.x;
  const int base = blockIdx.x * 512;
  for (int i = t; i < 512; i += 256) s[i] = (base + i < n) ? in[base + i] : 0;
  __syncthreads();
  for (int d = 1; d < 512; d <<= 1) {
    int stride = d * 2;
    int nidx = 512 / stride;
    if (t < nidx) {
      int idx = (t + 1) * stride - 1;
      s[idx] += s[idx - d];
    }
    __syncthreads();
  }
  if (t == 0) { total = s[511]; s[511] = 0; }
  __syncthreads();
  for (int d = 256; d >= 1; d >>= 1) {
    int stride = d * 2;
    int nidx = 512 / stride;
    if (t < nidx) {
      int idx = (t + 1) * stride - 1;
      int tmp = s[idx - d];
      s[idx - d] = s[idx];
      s[idx] += tmp;
    }
    __syncthreads();
  }
  for (int i = t; i < 512; i += 256)
    if (base + i < n) outp[base + i] = s[i];
  if (t == 0) bsum[blockIdx.x] = total;
}

// adds chunk offsets; writes BOTH off and off_mut
extern "C" __global__ __launch_bounds__(256) void k_scan_add(
    int* __restrict__ off, int* __restrict__ off_mut,
    const int* __restrict__ bofs, int n, int total) {
  int base = blockIdx.x * 512;
  int add = bofs[blockIdx.x];
  for (int i = threadIdx.x; i < 512; i += 256) {
    int idx = base + i;
    if (idx < n) {
      int val = off[idx] + add;
      off[idx] = val;
      off_mut[idx] = val;
    }
  }
  if (blockIdx.x == 0 && threadIdx.x == 0) off[n] = total;
}

// counting-sort the dst indices by src: dst_s[off[src]++] = dst
extern "C" __global__ __launch_bounds__(256) void k_scatter_dst(
    const int* __restrict__ src, const int* __restrict__ dstp,
    int* __restrict__ off_mut, int* __restrict__ dst_s, int nE) {
  int e = blockIdx.x * 256 + threadIdx.x;
  if (e >= nE) return;
  int pos = atomicAdd(&off_mut[src[e]], 1);
  dst_s[pos] = dstp[e];
}

// Fused edge phase -- exact round-11 config (proven 88 us floor).
// One wave per node, 4 groups x 16 lanes, one edge per group-iter,
// prefetch-1 pipeline. No max subtraction (|s| bounded; ratio identical).
extern "C" __global__ __launch_bounds__(256) void k_fused(
    const unsigned short* __restrict__ PQE, const int* __restrict__ off,
    const int* __restrict__ dst_s, const float* __restrict__ w0w,
    const float* __restrict__ w0b, float* __restrict__ U,
    float* __restrict__ ssum, int n) {
  int v = (blockIdx.x * 256 + threadIdx.x) >> 6;
  int lane = threadIdx.x & 63;
  if (v >= n) return;
  const int l16 = lane & 15;
  const int grp = lane >> 4;
  const int start = off[v], end = off[v + 1];
  const float K = 2.8853900817779268f;  // 2*log2(e)
  float q2[8], w[8];
  {
    uint4 qv = *(const uint4*)(PQE + (size_t)v * 384 + 256 + l16 * 8);
    unsigned qq[4] = {qv.x, qv.y, qv.z, qv.w};
    float4 wa = *(const float4*)&w0w[l16 * 8];
    float4 wc = *(const float4*)&w0w[l16 * 8 + 4];
    w[0] = wa.x; w[1] = wa.y; w[2] = wa.z; w[3] = wa.w;
    w[4] = wc.x; w[5] = wc.y; w[6] = wc.z; w[7] = wc.w;
#pragma unroll
    for (int j = 0; j < 8; ++j) q2[j] = K * bfu(qq[j >> 1], j & 1);
  }
  const float wb = w0b[0];
  float a[8] = {0.f, 0.f, 0.f, 0.f, 0.f, 0.f, 0.f, 0.f};
  float ssv = 0.f;
  int i = start + grp;
  uint4 pv, ev;
  if (i < end) {
    const unsigned short* pe = PQE + (size_t)dst_s[i] * 384 + l16 * 8;
    pv = *(const uint4*)pe;
    ev = *(const uint4*)(pe + 128);
  }
  while (i < end) {
    int inx = i + 4;
    uint4 pvn, evn;
    if (inx < end) {
      const unsigned short* pen = PQE + (size_t)dst_s[inx] * 384 + l16 * 8;
      pvn = *(const uint4*)pen;
      evn = *(const uint4*)(pen + 128);
    }
    unsigned pw[4] = {pv.x, pv.y, pv.z, pv.w};
    unsigned ew[4] = {ev.x, ev.y, ev.z, ev.w};
    float part = 0.f;
#pragma unroll
    for (int j = 0; j < 8; ++j) {
      float x = bfu(pw[j >> 1], j & 1);
      float e = exp2f(fmaf(x, K, q2[j]));
      float r = __builtin_amdgcn_rcpf(e + 1.0f);
      float t = fmaf(-2.0f, r, 1.0f);
      part = fmaf(t, w[j], part);
    }
    part += __shfl_xor(part, 8);
    part += __shfl_xor(part, 4);
    part += __shfl_xor(part, 2);
    part += __shfl_xor(part, 1);
    float p = __expf(part + wb);
    ssv += p;
#pragma unroll
    for (int j = 0; j < 8; ++j)
      a[j] = fmaf(p, bfu(ew[j >> 1], j & 1), a[j]);
    i = inx;
    pv = pvn;
    ev = evn;
  }
  // merge the 4 groups (disjoint edge subsets, same dim ownership)
#pragma unroll
  for (int j = 0; j < 8; ++j) {
    a[j] += __shfl_xor(a[j], 16);
    a[j] += __shfl_xor(a[j], 32);
  }
  ssv += __shfl_xor(ssv, 16);
  ssv += __shfl_xor(ssv, 32);
  if (grp == 0) {
    float4 o0 = make_float4(a[0], a[1], a[2], a[3]);
    float4 o1 = make_float4(a[4], a[5], a[6], a[7]);
    *(float4*)(U + (size_t)v * DD + l16 * 8) = o0;
    *(float4*)(U + (size_t)v * DD + l16 * 8 + 4) = o1;
    if (l16 == 0) ssum[v] = ssv;
  }
}

// out = tanh([emb | M] @ [Wself;Wneigh] + bself + tg*bneigh), M = U*inv + g*emb.
// emb-half A-frags read directly from PQE's E section (bf16, no conversion;
// lo-part dropped -- error ~6e-4). M-half keeps full hi/lo split.
// MFMA per ct: 4x2 (E) + 4x3 (M) = 20.
extern "C" __global__ __launch_bounds__(256) void k_out_mfma(
    const unsigned short* __restrict__ PQE, const float* __restrict__ emb,
    const float* __restrict__ U, const float* __restrict__ ssum,
    const float* __restrict__ g, const unsigned short* __restrict__ WBh,
    const unsigned short* __restrict__ WBl, const float* __restrict__ bself,
    const float* __restrict__ bneigh, float* __restrict__ out, int n) {
  const int wave = threadIdx.x >> 6, lane = threadIdx.x & 63;
  const int v0 = blockIdx.x * 64 + wave * 16;
  const int row = v0 + (lane & 15);
  const int kb = (lane >> 4) << 3;
  const bool rok = row < n;
  float inv = 0.f, gv = 0.f;
  if (rok) {
    float sv = ssum[row];
    inv = 1.f / (sv + 1e-9f);
    gv = g[row];
  }
  const s16x8 zf = {0, 0, 0, 0, 0, 0, 0, 0};
  s16x8 ae[4];          // emb half, direct bf16 from PQE E-section
#pragma unroll
  for (int ks = 0; ks < 4; ++ks) {
    ae[ks] = rok ? *(const s16x8*)(PQE + (size_t)row * 384 + 128 + ks * 32 + kb)
                 : zf;
  }
  s16x8 mh[4], ml[4];   // M half, hi/lo split
#pragma unroll
  for (int ks = 0; ks < 4; ++ks) {
    int k0 = ks * 32 + kb;
    float x[8] = {0.f, 0.f, 0.f, 0.f, 0.f, 0.f, 0.f, 0.f};
    if (rok) {
      float4 ea = *(const float4*)(emb + (size_t)row * DD + k0);
      float4 eb = *(const float4*)(emb + (size_t)row * DD + k0 + 4);
      float4 ua = *(const float4*)(U + (size_t)row * DD + k0);
      float4 ub = *(const float4*)(U + (size_t)row * DD + k0 + 4);
      x[0] = fmaf(gv, ea.x, ua.x * inv);
      x[1] = fmaf(gv, ea.y, ua.y * inv);
      x[2] = fmaf(gv, ea.z, ua.z * inv);
      x[3] = fmaf(gv, ea.w, ua.w * inv);
      x[4] = fmaf(gv, eb.x, ub.x * inv);
      x[5] = fmaf(gv, eb.y, ub.y * inv);
      x[6] = fmaf(gv, eb.z, ub.z * inv);
      x[7] = fmaf(gv, eb.w, ub.w * inv);
    }
    unsigned short hh[8], ll[8];
#pragma unroll
    for (int j = 0; j < 8; ++j) {
      unsigned short h = f2bf(x[j]);
      hh[j] = h;
      ll[j] = f2bf(x[j] - bf2f(h));
    }
    mh[ks] = *(const s16x8*)hh;
    ml[ks] = *(const s16x8*)ll;
  }
  f32x4 acc[8];
#pragma unroll
  for (int ct = 0; ct < 8; ++ct) acc[ct] = (f32x4)(0.f);
  const s16x8* wbh = (const s16x8*)WBh;
  const s16x8* wbl = (const s16x8*)WBl;
#pragma unroll
  for (int ct = 0; ct < 8; ++ct) {
#pragma unroll
    for (int ks = 0; ks < 4; ++ks) {
      s16x8 bh = wbh[(ct * 8 + ks) * 64 + lane];
      s16x8 bl = wbl[(ct * 8 + ks) * 64 + lane];
      acc[ct] = __builtin_amdgcn_mfma_f32_16x16x32_bf16(ae[ks], bh, acc[ct], 0, 0, 0);
      acc[ct] = __builtin_amdgcn_mfma_f32_16x16x32_bf16(ae[ks], bl, acc[ct], 0, 0, 0);
    }
#pragma unroll
    for (int ks = 0; ks < 4; ++ks) {
      s16x8 bh = wbh[(ct * 8 + 4 + ks) * 64 + lane];
      s16x8 bl = wbl[(ct * 8 + 4 + ks) * 64 + lane];
      acc[ct] = __builtin_amdgcn_mfma_f32_16x16x32_bf16(mh[ks], bh, acc[ct], 0, 0, 0);
      acc[ct] = __builtin_amdgcn_mfma_f32_16x16x32_bf16(ml[ks], bh, acc[ct], 0, 0, 0);
      acc[ct] = __builtin_amdgcn_mfma_f32_16x16x32_bf16(mh[ks], bl, acc[ct], 0, 0, 0);
    }
  }
  const int r0 = (lane >> 4) << 2;
  const int col0 = lane & 15;
  float tgr[4];
#pragma unroll
  for (int r = 0; r < 4; ++r) {
    int v = v0 + r0 + r;
    float tg = 0.f;
    if (v < n) {
      float sv = ssum[v];
      tg = sv / (sv + 1e-9f) + g[v];
    }
    tgr[r] = tg;
  }
#pragma unroll
  for (int ct = 0; ct < 8; ++ct) {
    int c = ct * 16 + col0;
    float bs = bself[c], bn = bneigh[c];
#pragma unroll
    for (int r = 0; r < 4; ++r) {
      int v = v0 + r0 + r;
      if (v < n) out[(size_t)v * DD + c] = tanh_fast(acc[ct][r] + bs + tgr[r] * bn);
    }
  }
}

static inline size_t al16(size_t x) { return (x + 15) & ~(size_t)15; }

extern "C" void kernel_launch(void* const* d_in, const int* in_sizes, int n_in,
                              void* d_out, int out_size, void* d_ws, size_t ws_size,
                              hipStream_t stream) {
  const float* emb = (const float*)d_in[0];
  const int* er_src = (const int*)d_in[1];
  const int* er_dst = (const int*)d_in[2];
  const int* ee_src = (const int*)d_in[3];
  const float* ee_w = (const float*)d_in[5];
  const float* Wattn = (const float*)d_in[6];
  const float* battn = (const float*)d_in[7];
  const float* w0w = (const float*)d_in[8];
  const float* w0b = (const float*)d_in[9];
  const float* Wself = (const float*)d_in[10];
  const float* bself = (const float*)d_in[11];
  const float* Wneigh = (const float*)d_in[12];
  const float* bneigh = (const float*)d_in[13];
  const int n = in_sizes[0] / DD;
  const int nER = in_sizes[1];
  const int nEE = in_sizes[3];

  // workspace layout (16B-aligned slices)
  char* w = (char*)d_ws;
  size_t o = 0;
  unsigned short* PQE = (unsigned short*)(w + o); o += al16((size_t)n * 384 * 2);
  float* U = (float*)(w + o);   o += al16((size_t)n * DD * 4);
  int* dst_s = (int*)(w + o);   o += al16((size_t)nER * 4);
  int* count = (int*)(w + o);   o += al16((size_t)n * 4);
  float* g = (float*)(w + o);   o += al16((size_t)n * 4);   // adjacent to count
  int* off = (int*)(w + o);     o += al16((size_t)(n + 4) * 4);
  int* off_mut = (int*)(w + o); o += al16((size_t)n * 4);
  float* ssum = (float*)(w + o); o += al16((size_t)n * 4);
  unsigned short* WB = (unsigned short*)(w + o);   o += 65536;
  unsigned short* WB2h = (unsigned short*)(w + o); o += 65536;
  unsigned short* WB2l = (unsigned short*)(w + o); o += 65536;
  int* bsum = (int*)(w + o);    o += 4096;
  int* dummy = (int*)(w + o);   o += 64;

  const int nb = (n + 511) / 512;
  const int hb = (nER + 255) / 256;
  const int db = (nEE + 255) / 256;

  hipMemsetAsync(count, 0, (size_t)n * 8, stream);  // count + g

  k_misc<<<32 + hb + db, 256, 0, stream>>>(Wattn, WB, Wself, Wneigh, WB2h, WB2l,
                                           er_src, count, nER, hb, ee_src, ee_w,
                                           g, nEE);
  k_pq_mfma<<<(n + 63) / 64, 256, 0, stream>>>(emb, WB, battn, PQE, n);
  k_scan<<<nb, 256, 0, stream>>>(count, off, bsum, n);
  k_scan<<<1, 256, 0, stream>>>(bsum, bsum, dummy, nb);
  k_scan_add<<<nb, 256, 0, stream>>>(off, off_mut, bsum, n, nER);
  k_scatter_dst<<<(nER + 255) / 256, 256, 0, stream>>>(er_src, er_dst, off_mut,
                                                       dst_s, nER);
  k_fused<<<(n + 3) / 4, 256, 0, stream>>>(PQE, off, dst_s, w0w, w0b,
                                           U, ssum, n);
  k_out_mfma<<<(n + 63) / 64, 256, 0, stream>>>(PQE, emb, U, ssum, g, WB2h,
                                                WB2l, bself, bneigh,
                                                (float*)d_out, n);
}

// Round 19
// 326.655 us; speedup vs baseline: 1.0654x; 1.0382x over previous
//
#include <hip/hip_runtime.h>

#define DD 128

typedef short s16x8 __attribute__((ext_vector_type(8)));
typedef float f32x4 __attribute__((ext_vector_type(4)));

// tanh via hardware rcp: 1 - 2/(e^{2x}+1). v_rcp_f32 is ~1 ulp.
__device__ __forceinline__ float tanh_fast(float x) {
  float e = __expf(2.0f * x);
  float r = __builtin_amdgcn_rcpf(e + 1.0f);
  return fmaf(-2.0f, r, 1.0f);
}

// f32 -> bf16 round-to-nearest-even
__device__ __forceinline__ unsigned short f2bf(float f) {
  unsigned u = __float_as_uint(f);
  u += 0x7FFFu + ((u >> 16) & 1u);
  return (unsigned short)(u >> 16);
}

__device__ __forceinline__ float bf2f(unsigned short u) {
  return __uint_as_float(((unsigned)u) << 16);
}

// unpack bf16 pair word: odd ? hi : lo  (1 VALU op each)
__device__ __forceinline__ float bfu(unsigned w, int odd) {
  return __uint_as_float(odd ? (w & 0xFFFF0000u) : (w << 16));
}

// ---- misc pass: [0,16) packw1 | [16,32) packw2 | [32,32+hb) ER hist |
//      [32+hb, 32+hb+db) EE weighted degree ----
extern "C" __global__ __launch_bounds__(256) void k_misc(
    const float* __restrict__ Wattn, unsigned short* __restrict__ WB,
    const float* __restrict__ Wself, const float* __restrict__ Wneigh,
    unsigned short* __restrict__ WBh, unsigned short* __restrict__ WBl,
    const int* __restrict__ er_src, int* __restrict__ count, int nER, int hb,
    const int* __restrict__ ee_src, const float* __restrict__ ee_w,
    float* __restrict__ g, int nEE) {
  const int b = blockIdx.x;
  const int tid = threadIdx.x;
  if (b < 16) {
    int t = b * 256 + tid;      // 0..4095
    int lane = t & 63;
    int cks = t >> 6;           // ct*4+ks
    int ks = cks & 3, ct = cks >> 2;
    int c = ct * 16 + (lane & 15);
    int kb = ks * 32 + ((lane >> 4) << 3);
    const float* srcp = (c < DD) ? (Wattn + (size_t)kb * DD + c)
                                 : (Wattn + (size_t)(DD + kb) * DD + (c - DD));
    unsigned short* dst = WB + (size_t)t * 8;
#pragma unroll
    for (int j = 0; j < 8; ++j) dst[j] = f2bf(srcp[(size_t)j * DD]);
  } else if (b < 32) {
    int t = (b - 16) * 256 + tid;  // 0..4095
    int lane = t & 63;
    int cks = t >> 6;           // ct*8+ks
    int ks = cks & 7, ct = cks >> 3;
    int c = ct * 16 + (lane & 15);
    int k0 = ks * 32 + ((lane >> 4) << 3);
#pragma unroll
    for (int j = 0; j < 8; ++j) {
      int k = k0 + j;
      float v = (k < DD) ? Wself[(size_t)k * DD + c]
                         : Wneigh[(size_t)(k - DD) * DD + c];
      unsigned short h = f2bf(v);
      float r = v - bf2f(h);
      WBh[(size_t)t * 8 + j] = h;
      WBl[(size_t)t * 8 + j] = f2bf(r);
    }
  } else if (b < 32 + hb) {
    int e = (b - 32) * 256 + tid;
    if (e < nER) atomicAdd(&count[er_src[e]], 1);
  } else {
    int e = (b - 32 - hb) * 256 + tid;
    if (e < nEE) unsafeAtomicAdd(&g[ee_src[e]], ee_w[e]);
  }
}

// PQE[v] (stride 384 shorts): [0:128)=P, [128:256)=E, [256:384)=Q, bf16.
// Staged in LDS, then one contiguous coalesced write.
extern "C" __global__ __launch_bounds__(256) void k_pq_mfma(
    const float* __restrict__ emb, const unsigned short* __restrict__ WB,
    const float* __restrict__ battn, unsigned short* __restrict__ PQE, int n) {
  __shared__ unsigned short S[64][388];
  const int wave = threadIdx.x >> 6, lane = threadIdx.x & 63;
  const int v0b = blockIdx.x * 64;
  const int v0 = v0b + wave * 16;
  const int row = v0 + (lane & 15);
  const int lr = wave * 16 + (lane & 15);
  const int kb = (lane >> 4) << 3;
  const bool rok = row < n;
  s16x8 a[4];
#pragma unroll
  for (int ks = 0; ks < 4; ++ks) {
    unsigned short tmp[8] = {0, 0, 0, 0, 0, 0, 0, 0};
    if (rok) {
      float4 xa = *(const float4*)(emb + (size_t)row * DD + ks * 32 + kb);
      float4 xb = *(const float4*)(emb + (size_t)row * DD + ks * 32 + kb + 4);
      tmp[0] = f2bf(xa.x); tmp[1] = f2bf(xa.y);
      tmp[2] = f2bf(xa.z); tmp[3] = f2bf(xa.w);
      tmp[4] = f2bf(xb.x); tmp[5] = f2bf(xb.y);
      tmp[6] = f2bf(xb.z); tmp[7] = f2bf(xb.w);
    }
    a[ks] = *(const s16x8*)tmp;
    *(s16x8*)&S[lr][128 + ks * 32 + kb] = a[ks];   // E copy
  }
  f32x4 acc[16];
#pragma unroll
  for (int ct = 0; ct < 16; ++ct) acc[ct] = (f32x4)(0.f);
  const s16x8* wb = (const s16x8*)WB;
#pragma unroll
  for (int ct = 0; ct < 16; ++ct) {
#pragma unroll
    for (int ks = 0; ks < 4; ++ks) {
      s16x8 b = wb[(ct * 4 + ks) * 64 + lane];
      acc[ct] = __builtin_amdgcn_mfma_f32_16x16x32_bf16(a[ks], b, acc[ct], 0, 0, 0);
    }
  }
  const int r0 = (lane >> 4) << 2;
  const int col0 = lane & 15;
#pragma unroll
  for (int ct = 0; ct < 16; ++ct) {
    int c = ct * 16 + col0;
    float bias = (c < DD) ? battn[c] : 0.f;
    int dsto = (c < DD) ? c : (c + DD);   // P at [0,128), Q at [256,384)
#pragma unroll
    for (int r = 0; r < 4; ++r)
      S[wave * 16 + r0 + r][dsto] = f2bf(acc[ct][r] + bias);
  }
  __syncthreads();
  const int tid = threadIdx.x;
#pragma unroll
  for (int i = 0; i < 12; ++i) {
    int idx = tid + i * 256;          // 0..3071
    int rr = idx / 48, k8 = idx - rr * 48;
    if (v0b + rr < n) {
      uint4 val = *(const uint4*)&S[rr][k8 * 8];
      *(uint4*)(PQE + (size_t)(v0b + rr) * 384 + k8 * 8) = val;
    }
  }
}

// Blelloch exclusive scan, 512 elems/block; bsum[b] = chunk total
extern "C" __global__ __launch_bounds__(256) void k_scan(
    const int* __restrict__ in, int* __restrict__ outp,
    int* __restrict__ bsum, int n) {
  __shared__ int s[512];
  __shared__ int total;
  const int t = threadIdx.x;
  const int base = blockIdx.x * 512;
  for (int i = t; i < 512; i += 256) s[i] = (base + i < n) ? in[base + i] : 0;
  __syncthreads();
  for (int d = 1; d < 512; d <<= 1) {
    int stride = d * 2;
    int nidx = 512 / stride;
    if (t < nidx) {
      int idx = (t + 1) * stride - 1;
      s[idx] += s[idx - d];
    }
    __syncthreads();
  }
  if (t == 0) { total = s[511]; s[511] = 0; }
  __syncthreads();
  for (int d = 256; d >= 1; d >>= 1) {
    int stride = d * 2;
    int nidx = 512 / stride;
    if (t < nidx) {
      int idx = (t + 1) * stride - 1;
      int tmp = s[idx - d];
      s[idx - d] = s[idx];
      s[idx] += tmp;
    }
    __syncthreads();
  }
  for (int i = t; i < 512; i += 256)
    if (base + i < n) outp[base + i] = s[i];
  if (t == 0) bsum[blockIdx.x] = total;
}

// adds chunk offsets; writes BOTH off and off_mut
extern "C" __global__ __launch_bounds__(256) void k_scan_add(
    int* __restrict__ off, int* __restrict__ off_mut,
    const int* __restrict__ bofs, int n, int total) {
  int base = blockIdx.x * 512;
  int add = bofs[blockIdx.x];
  for (int i = threadIdx.x; i < 512; i += 256) {
    int idx = base + i;
    if (idx < n) {
      int val = off[idx] + add;
      off[idx] = val;
      off_mut[idx] = val;
    }
  }
  if (blockIdx.x == 0 && threadIdx.x == 0) off[n] = total;
}

// counting-sort the dst indices by src: dst_s[off[src]++] = dst
extern "C" __global__ __launch_bounds__(256) void k_scatter_dst(
    const int* __restrict__ src, const int* __restrict__ dstp,
    int* __restrict__ off_mut, int* __restrict__ dst_s, int nE) {
  int e = blockIdx.x * 256 + threadIdx.x;
  if (e >= nE) return;
  int pos = atomicAdd(&off_mut[src[e]], 1);
  dst_s[pos] = dstp[e];
}

// Fused edge phase (round-11 config: proven 88 us floor) + M epilogue.
// One wave per node, 4 groups x 16 lanes, one edge per group-iter,
// prefetch-1 pipeline. No max subtraction (|s| bounded; ratio identical).
// Epilogue (per node, grp 0): M = U*inv + g*emb computed in-register,
// stored as bf16 hi/lo (MBh/MBl); tg = ssum/(ssum+1e-9)+g precomputed.
// This removes k_out's 51MB U read + 51MB emb read + all conversions.
extern "C" __global__ __launch_bounds__(256) void k_fused(
    const unsigned short* __restrict__ PQE, const int* __restrict__ off,
    const int* __restrict__ dst_s, const float* __restrict__ w0w,
    const float* __restrict__ w0b, const float* __restrict__ emb,
    const float* __restrict__ g, unsigned short* __restrict__ MBh,
    unsigned short* __restrict__ MBl, float* __restrict__ tgb, int n) {
  int v = (blockIdx.x * 256 + threadIdx.x) >> 6;
  int lane = threadIdx.x & 63;
  if (v >= n) return;
  const int l16 = lane & 15;
  const int grp = lane >> 4;
  const int start = off[v], end = off[v + 1];
  const float K = 2.8853900817779268f;  // 2*log2(e)
  float q2[8], w[8];
  {
    uint4 qv = *(const uint4*)(PQE + (size_t)v * 384 + 256 + l16 * 8);
    unsigned qq[4] = {qv.x, qv.y, qv.z, qv.w};
    float4 wa = *(const float4*)&w0w[l16 * 8];
    float4 wc = *(const float4*)&w0w[l16 * 8 + 4];
    w[0] = wa.x; w[1] = wa.y; w[2] = wa.z; w[3] = wa.w;
    w[4] = wc.x; w[5] = wc.y; w[6] = wc.z; w[7] = wc.w;
#pragma unroll
    for (int j = 0; j < 8; ++j) q2[j] = K * bfu(qq[j >> 1], j & 1);
  }
  const float wb = w0b[0];
  float a[8] = {0.f, 0.f, 0.f, 0.f, 0.f, 0.f, 0.f, 0.f};
  float ssv = 0.f;
  int i = start + grp;
  uint4 pv, ev;
  if (i < end) {
    const unsigned short* pe = PQE + (size_t)dst_s[i] * 384 + l16 * 8;
    pv = *(const uint4*)pe;
    ev = *(const uint4*)(pe + 128);
  }
  while (i < end) {
    int inx = i + 4;
    uint4 pvn, evn;
    if (inx < end) {
      const unsigned short* pen = PQE + (size_t)dst_s[inx] * 384 + l16 * 8;
      pvn = *(const uint4*)pen;
      evn = *(const uint4*)(pen + 128);
    }
    unsigned pw[4] = {pv.x, pv.y, pv.z, pv.w};
    unsigned ew[4] = {ev.x, ev.y, ev.z, ev.w};
    float part = 0.f;
#pragma unroll
    for (int j = 0; j < 8; ++j) {
      float x = bfu(pw[j >> 1], j & 1);
      float e = exp2f(fmaf(x, K, q2[j]));
      float r = __builtin_amdgcn_rcpf(e + 1.0f);
      float t = fmaf(-2.0f, r, 1.0f);
      part = fmaf(t, w[j], part);
    }
    part += __shfl_xor(part, 8);
    part += __shfl_xor(part, 4);
    part += __shfl_xor(part, 2);
    part += __shfl_xor(part, 1);
    float p = __expf(part + wb);
    ssv += p;
#pragma unroll
    for (int j = 0; j < 8; ++j)
      a[j] = fmaf(p, bfu(ew[j >> 1], j & 1), a[j]);
    i = inx;
    pv = pvn;
    ev = evn;
  }
  // merge the 4 groups (disjoint edge subsets, same dim ownership)
#pragma unroll
  for (int j = 0; j < 8; ++j) {
    a[j] += __shfl_xor(a[j], 16);
    a[j] += __shfl_xor(a[j], 32);
  }
  ssv += __shfl_xor(ssv, 16);
  ssv += __shfl_xor(ssv, 32);
  if (grp == 0) {
    float inv = 1.0f / (ssv + 1e-9f);
    float gv = g[v];
    float4 ea = *(const float4*)(emb + (size_t)v * DD + l16 * 8);
    float4 eb = *(const float4*)(emb + (size_t)v * DD + l16 * 8 + 4);
    float m[8];
    m[0] = fmaf(gv, ea.x, a[0] * inv);
    m[1] = fmaf(gv, ea.y, a[1] * inv);
    m[2] = fmaf(gv, ea.z, a[2] * inv);
    m[3] = fmaf(gv, ea.w, a[3] * inv);
    m[4] = fmaf(gv, eb.x, a[4] * inv);
    m[5] = fmaf(gv, eb.y, a[5] * inv);
    m[6] = fmaf(gv, eb.z, a[6] * inv);
    m[7] = fmaf(gv, eb.w, a[7] * inv);
    unsigned short hh[8], ll[8];
#pragma unroll
    for (int j = 0; j < 8; ++j) {
      unsigned short h = f2bf(m[j]);
      hh[j] = h;
      ll[j] = f2bf(m[j] - bf2f(h));
    }
    *(s16x8*)(MBh + (size_t)v * DD + l16 * 8) = *(const s16x8*)hh;
    *(s16x8*)(MBl + (size_t)v * DD + l16 * 8) = *(const s16x8*)ll;
    if (l16 == 0) tgb[v] = ssv / (ssv + 1e-9f) + gv;
  }
}

// out = tanh([emb | M] @ [Wself;Wneigh] + bself + tg*bneigh).
// A-frags: emb half direct bf16 from PQE E-section (lo dropped, err ~6e-4);
// M half from precomputed MBh/MBl (hi/lo). MFMA per ct: 4x2 + 4x3 = 20.
extern "C" __global__ __launch_bounds__(256) void k_out_mfma(
    const unsigned short* __restrict__ PQE, const unsigned short* __restrict__ MBh,
    const unsigned short* __restrict__ MBl, const float* __restrict__ tgb,
    const unsigned short* __restrict__ WBh, const unsigned short* __restrict__ WBl,
    const float* __restrict__ bself, const float* __restrict__ bneigh,
    float* __restrict__ out, int n) {
  const int wave = threadIdx.x >> 6, lane = threadIdx.x & 63;
  const int v0 = blockIdx.x * 64 + wave * 16;
  const int row = v0 + (lane & 15);
  const int kb = (lane >> 4) << 3;
  const bool rok = row < n;
  const s16x8 zf = {0, 0, 0, 0, 0, 0, 0, 0};
  s16x8 ae[4], mh[4], ml[4];
#pragma unroll
  for (int ks = 0; ks < 4; ++ks) {
    int k0 = ks * 32 + kb;
    ae[ks] = rok ? *(const s16x8*)(PQE + (size_t)row * 384 + 128 + k0) : zf;
    mh[ks] = rok ? *(const s16x8*)(MBh + (size_t)row * DD + k0) : zf;
    ml[ks] = rok ? *(const s16x8*)(MBl + (size_t)row * DD + k0) : zf;
  }
  f32x4 acc[8];
#pragma unroll
  for (int ct = 0; ct < 8; ++ct) acc[ct] = (f32x4)(0.f);
  const s16x8* wbh = (const s16x8*)WBh;
  const s16x8* wbl = (const s16x8*)WBl;
#pragma unroll
  for (int ct = 0; ct < 8; ++ct) {
#pragma unroll
    for (int ks = 0; ks < 4; ++ks) {
      s16x8 bh = wbh[(ct * 8 + ks) * 64 + lane];
      s16x8 bl = wbl[(ct * 8 + ks) * 64 + lane];
      acc[ct] = __builtin_amdgcn_mfma_f32_16x16x32_bf16(ae[ks], bh, acc[ct], 0, 0, 0);
      acc[ct] = __builtin_amdgcn_mfma_f32_16x16x32_bf16(ae[ks], bl, acc[ct], 0, 0, 0);
    }
#pragma unroll
    for (int ks = 0; ks < 4; ++ks) {
      s16x8 bh = wbh[(ct * 8 + 4 + ks) * 64 + lane];
      s16x8 bl = wbl[(ct * 8 + 4 + ks) * 64 + lane];
      acc[ct] = __builtin_amdgcn_mfma_f32_16x16x32_bf16(mh[ks], bh, acc[ct], 0, 0, 0);
      acc[ct] = __builtin_amdgcn_mfma_f32_16x16x32_bf16(ml[ks], bh, acc[ct], 0, 0, 0);
      acc[ct] = __builtin_amdgcn_mfma_f32_16x16x32_bf16(mh[ks], bl, acc[ct], 0, 0, 0);
    }
  }
  const int r0 = (lane >> 4) << 2;
  const int col0 = lane & 15;
  float tgr[4];
#pragma unroll
  for (int r = 0; r < 4; ++r) {
    int v = v0 + r0 + r;
    tgr[r] = (v < n) ? tgb[v] : 0.f;
  }
#pragma unroll
  for (int ct = 0; ct < 8; ++ct) {
    int c = ct * 16 + col0;
    float bs = bself[c], bn = bneigh[c];
#pragma unroll
    for (int r = 0; r < 4; ++r) {
      int v = v0 + r0 + r;
      if (v < n) out[(size_t)v * DD + c] = tanh_fast(acc[ct][r] + bs + tgr[r] * bn);
    }
  }
}

static inline size_t al16(size_t x) { return (x + 15) & ~(size_t)15; }

extern "C" void kernel_launch(void* const* d_in, const int* in_sizes, int n_in,
                              void* d_out, int out_size, void* d_ws, size_t ws_size,
                              hipStream_t stream) {
  const float* emb = (const float*)d_in[0];
  const int* er_src = (const int*)d_in[1];
  const int* er_dst = (const int*)d_in[2];
  const int* ee_src = (const int*)d_in[3];
  const float* ee_w = (const float*)d_in[5];
  const float* Wattn = (const float*)d_in[6];
  const float* battn = (const float*)d_in[7];
  const float* w0w = (const float*)d_in[8];
  const float* w0b = (const float*)d_in[9];
  const float* Wself = (const float*)d_in[10];
  const float* bself = (const float*)d_in[11];
  const float* Wneigh = (const float*)d_in[12];
  const float* bneigh = (const float*)d_in[13];
  const int n = in_sizes[0] / DD;
  const int nER = in_sizes[1];
  const int nEE = in_sizes[3];

  // workspace layout (16B-aligned slices)
  char* w = (char*)d_ws;
  size_t o = 0;
  unsigned short* PQE = (unsigned short*)(w + o); o += al16((size_t)n * 384 * 2);
  unsigned short* MBh = (unsigned short*)(w + o); o += al16((size_t)n * DD * 2);
  unsigned short* MBl = (unsigned short*)(w + o); o += al16((size_t)n * DD * 2);
  int* dst_s = (int*)(w + o);   o += al16((size_t)nER * 4);
  int* count = (int*)(w + o);   o += al16((size_t)n * 4);
  float* g = (float*)(w + o);   o += al16((size_t)n * 4);   // adjacent to count
  int* off = (int*)(w + o);     o += al16((size_t)(n + 4) * 4);
  int* off_mut = (int*)(w + o); o += al16((size_t)n * 4);
  float* tgb = (float*)(w + o); o += al16((size_t)n * 4);
  unsigned short* WB = (unsigned short*)(w + o);   o += 65536;
  unsigned short* WB2h = (unsigned short*)(w + o); o += 65536;
  unsigned short* WB2l = (unsigned short*)(w + o); o += 65536;
  int* bsum = (int*)(w + o);    o += 4096;
  int* dummy = (int*)(w + o);   o += 64;

  const int nb = (n + 511) / 512;
  const int hb = (nER + 255) / 256;
  const int db = (nEE + 255) / 256;

  hipMemsetAsync(count, 0, (size_t)n * 8, stream);  // count + g

  k_misc<<<32 + hb + db, 256, 0, stream>>>(Wattn, WB, Wself, Wneigh, WB2h, WB2l,
                                           er_src, count, nER, hb, ee_src, ee_w,
                                           g, nEE);
  k_pq_mfma<<<(n + 63) / 64, 256, 0, stream>>>(emb, WB, battn, PQE, n);
  k_scan<<<nb, 256, 0, stream>>>(count, off, bsum, n);
  k_scan<<<1, 256, 0, stream>>>(bsum, bsum, dummy, nb);
  k_scan_add<<<nb, 256, 0, stream>>>(off, off_mut, bsum, n, nER);
  k_scatter_dst<<<(nER + 255) / 256, 256, 0, stream>>>(er_src, er_dst, off_mut,
                                                       dst_s, nER);
  k_fused<<<(n + 3) / 4, 256, 0, stream>>>(PQE, off, dst_s, w0w, w0b, emb, g,
                                           MBh, MBl, tgb, n);
  k_out_mfma<<<(n + 63) / 64, 256, 0, stream>>>(PQE, MBh, MBl, tgb, WB2h, WB2l,
                                                bself, bneigh, (float*)d_out, n);
}